// Round 1
// baseline (696.251 us; speedup 1.0000x reference)
//
#include <hip/hip_runtime.h>

// Problem constants
#define LQN   16384     // queries per batch (128*128)
#define LINN  65536     // value length per batch (4 levels * 16384)

typedef __attribute__((ext_vector_type(8))) short bf16x8;
typedef __attribute__((ext_vector_type(4))) float f32x4;
typedef __attribute__((ext_vector_type(4))) unsigned short bf16x4;

__device__ __forceinline__ unsigned short f2bf(float f) {
  unsigned u = __float_as_uint(f);
  u += 0x7FFFu + ((u >> 16) & 1u);      // round-to-nearest-even
  return (unsigned short)(u >> 16);
}

// ---------------- weight transpose+convert: W (K x N) f32 -> Wt (N x K) bf16
__global__ __launch_bounds__(256) void wtrans_kernel(const float* __restrict__ W,
                                                     unsigned short* __restrict__ Wt,
                                                     int K, int N) {
  int idx = blockIdx.x * 256 + threadIdx.x;   // grid sized exactly K*N/256
  int n = idx / K, k = idx - n * K;
  Wt[idx] = f2bf(W[(size_t)k * N + n]);
}

// ---------------- q = cur_src + pos[:, 3]  (f32 -> bf16)
__global__ __launch_bounds__(256) void q_kernel(const float* __restrict__ cur,
                                                const float* __restrict__ pos,
                                                unsigned short* __restrict__ q) {
  size_t i = (size_t)blockIdx.x * 256 + threadIdx.x;  // float4 index, 2,097,152 total
  size_t row = i >> 6;                                // row in [0, 32768)
  int n = (int)(row >> 14), lq = (int)(row & 16383);
  float4 a = ((const float4*)cur)[i];
  float4 b = ((const float4*)pos)[(((size_t)n * 4 + 3) * LQN + lq) * 64 + (i & 63)];
  bf16x4 o;
  o.x = f2bf(a.x + b.x); o.y = f2bf(a.y + b.y);
  o.z = f2bf(a.z + b.z); o.w = f2bf(a.w + b.w);
  ((bf16x4*)q)[i] = o;
}

// ---------------- bf16 MFMA GEMM: C(MxN) = A(MxK) [+A2] @ B(KxN) + bias
// Bt is B pre-transposed to N x K bf16. 128x128 tile, BK=64, 4 waves (2x2 of 64x64).
template <int A_BF16, int HAS_A2, int DO_RELU, int OUT_BF16>
__global__ __launch_bounds__(256) void gemm_kernel(
    const void* __restrict__ Ap, const float* __restrict__ A2,
    const unsigned short* __restrict__ Bt, const float* __restrict__ bias,
    void* __restrict__ Cp, int M, int N, int K) {
  __shared__ unsigned short As[128][72];   // 64 + 8 pad (rows 144 B, 16B-aligned)
  __shared__ unsigned short Bs[128][72];
  const int tid = threadIdx.x;
  const int m0 = blockIdx.x * 128, n0 = blockIdx.y * 128;
  const int wave = tid >> 6, lane = tid & 63;
  const int wm = (wave >> 1) * 64, wn = (wave & 1) * 64;
  const int l15 = lane & 15, quad = lane >> 4;

  f32x4 acc[4][4];
#pragma unroll
  for (int i = 0; i < 4; i++)
#pragma unroll
    for (int j = 0; j < 4; j++)
#pragma unroll
      for (int r = 0; r < 4; r++) acc[i][j][r] = 0.f;

  for (int k0 = 0; k0 < K; k0 += 64) {
    // ---- stage A tile (128 x 64)
    if (A_BF16) {
      const unsigned short* A = (const unsigned short*)Ap;
#pragma unroll
      for (int j = 0; j < 4; j++) {
        int c = tid + j * 256;                 // chunk of 8 bf16
        int row = c >> 3, ks = (c & 7) * 8;
        bf16x8 v = *(const bf16x8*)(A + (size_t)(m0 + row) * K + k0 + ks);
        *(bf16x8*)&As[row][ks] = v;
      }
    } else {
      const float* A = (const float*)Ap;
#pragma unroll
      for (int j = 0; j < 8; j++) {
        int c = tid + j * 256;                 // chunk of 4 f32
        int row = c >> 4, ks = (c & 15) * 4;
        float4 v = *(const float4*)(A + (size_t)(m0 + row) * K + k0 + ks);
        if (HAS_A2) {
          float4 w = *(const float4*)(A2 + (size_t)(m0 + row) * K + k0 + ks);
          v.x += w.x; v.y += w.y; v.z += w.z; v.w += w.w;
        }
        bf16x4 b;
        b.x = f2bf(v.x); b.y = f2bf(v.y); b.z = f2bf(v.z); b.w = f2bf(v.w);
        *(bf16x4*)&As[row][ks] = b;
      }
    }
    // ---- stage B tile (128 n-rows x 64 k), already bf16 N x K
#pragma unroll
    for (int j = 0; j < 4; j++) {
      int c = tid + j * 256;
      int row = c >> 3, ks = (c & 7) * 8;
      bf16x8 v = *(const bf16x8*)(Bt + (size_t)(n0 + row) * K + k0 + ks);
      *(bf16x8*)&Bs[row][ks] = v;
    }
    __syncthreads();
#pragma unroll
    for (int kk = 0; kk < 64; kk += 32) {
      bf16x8 af[4], bfr[4];
#pragma unroll
      for (int i = 0; i < 4; i++) af[i] = *(const bf16x8*)&As[wm + i * 16 + l15][kk + quad * 8];
#pragma unroll
      for (int j = 0; j < 4; j++) bfr[j] = *(const bf16x8*)&Bs[wn + j * 16 + l15][kk + quad * 8];
#pragma unroll
      for (int i = 0; i < 4; i++)
#pragma unroll
        for (int j = 0; j < 4; j++)
          acc[i][j] = __builtin_amdgcn_mfma_f32_16x16x32_bf16(af[i], bfr[j], acc[i][j], 0, 0, 0);
    }
    __syncthreads();
  }
  // ---- epilogue: bias (+relu), store
#pragma unroll
  for (int i = 0; i < 4; i++) {
#pragma unroll
    for (int j = 0; j < 4; j++) {
      const int col = n0 + wn + j * 16 + l15;
      const float bv = bias[col];
#pragma unroll
      for (int r = 0; r < 4; r++) {
        const int row = m0 + wm + i * 16 + quad * 4 + r;
        float v = acc[i][j][r] + bv;
        if (DO_RELU) v = fmaxf(v, 0.f);
        if (OUT_BF16)
          ((unsigned short*)Cp)[(size_t)row * N + col] = f2bf(v);
        else
          ((float*)Cp)[(size_t)row * N + col] = v;
      }
    }
  }
}

// ---------------- deformable sampling
// value: (2, LINN, 8, 32) bf16; offs: (2,LQ,8,4,4,2) f32; attnl: (2,LQ,128) f32;
// refp: (2,LQ,4,2) f32; out: (2,LQ,8,32) bf16 written as uint pairs.
// 16-lane subgroup per (n,lq,h); lane c handles channels 2c,2c+1.
__global__ __launch_bounds__(256) void sample_kernel(
    const unsigned short* __restrict__ value, const float* __restrict__ offs,
    const float* __restrict__ attnl, const float* __restrict__ refp,
    unsigned int* __restrict__ attn_out) {
  const int tid = threadIdx.x;
  const int sub = tid >> 4;
  const int c = tid & 15;
  const int g = blockIdx.x * 16 + sub;     // (n*LQ+lq)*8 + h, < 262144
  const int n = g >> 17;
  const int nl = g >> 3;                   // n*LQ + lq
  const int h = g & 7;

  // softmax over the 16 (level,point) logits (redundant per lane; broadcast loads)
  const float* lg = attnl + (size_t)nl * 128 + h * 16;
  float e[16];
  float mx = -1e30f;
#pragma unroll
  for (int i = 0; i < 16; i++) { e[i] = lg[i]; mx = fmaxf(mx, e[i]); }
  float s = 0.f;
#pragma unroll
  for (int i = 0; i < 16; i++) { e[i] = __expf(e[i] - mx); s += e[i]; }
  const float inv = 1.f / s;

  // this lane preps point pt = c (c in [0,16))
  const int pt = c;
  const int pl = pt >> 2;
  const float ox = offs[((size_t)g * 16 + pt) * 2 + 0];
  const float oy = offs[((size_t)g * 16 + pt) * 2 + 1];
  const float rx = refp[((size_t)nl * 4 + pl) * 2 + 0];
  const float ry = refp[((size_t)nl * 4 + pl) * 2 + 1];
  const float x = fmaf(rx, 128.f, ox - 0.5f);   // (ref + off/128)*128 - 0.5
  const float y = fmaf(ry, 128.f, oy - 0.5f);
  const float xf = floorf(x), yf = floorf(y);
  const float fx = x - xf, fy = y - yf;
  const int x0 = (int)xf, y0 = (int)yf;
  const float aw = e[pt] * inv;
  const int xc0 = min(max(x0, 0), 127), xc1 = min(max(x0 + 1, 0), 127);
  const int yc0 = min(max(y0, 0), 127), yc1 = min(max(y0 + 1, 0), 127);
  float wx0 = (x0 >= 0 && x0 <= 127) ? (1.f - fx) : 0.f;
  float wx1 = (x0 >= -1 && x0 <= 126) ? fx : 0.f;
  float wy0 = ((y0 >= 0 && y0 <= 127) ? (1.f - fy) : 0.f) * aw;
  float wy1 = ((y0 >= -1 && y0 <= 126) ? fy : 0.f) * aw;
  const int packed = xc0 | (xc1 << 7) | (yc0 << 14) | (yc1 << 21);

  // base pointer (uint = 2 channels); pixel stride = 256 bf16 = 128 uint
  const unsigned int* base0 =
      (const unsigned int*)value + (((size_t)n * LINN) * 8 + h) * 16 + c;

  float a0 = 0.f, a1 = 0.f;
#pragma unroll
  for (int p = 0; p < 16; p++) {
    const int pk = __shfl(packed, p, 16);
    const float w_x0 = __shfl(wx0, p, 16);
    const float w_x1 = __shfl(wx1, p, 16);
    const float w_y0 = __shfl(wy0, p, 16);
    const float w_y1 = __shfl(wy1, p, 16);
    const unsigned int* bl = base0 + (size_t)(p >> 2) * (LQN * 128);
    const int X0 = pk & 127, X1 = (pk >> 7) & 127;
    const int Y0 = (pk >> 14) & 127, Y1 = (pk >> 21) & 127;
    const unsigned v00 = bl[(Y0 * 128 + X0) * 128];
    const unsigned v01 = bl[(Y0 * 128 + X1) * 128];
    const unsigned v10 = bl[(Y1 * 128 + X0) * 128];
    const unsigned v11 = bl[(Y1 * 128 + X1) * 128];
    const float w00 = w_x0 * w_y0, w01 = w_x1 * w_y0;
    const float w10 = w_x0 * w_y1, w11 = w_x1 * w_y1;
    a0 = fmaf(w00, __uint_as_float(v00 << 16), a0);
    a1 = fmaf(w00, __uint_as_float(v00 & 0xFFFF0000u), a1);
    a0 = fmaf(w01, __uint_as_float(v01 << 16), a0);
    a1 = fmaf(w01, __uint_as_float(v01 & 0xFFFF0000u), a1);
    a0 = fmaf(w10, __uint_as_float(v10 << 16), a0);
    a1 = fmaf(w10, __uint_as_float(v10 & 0xFFFF0000u), a1);
    a0 = fmaf(w11, __uint_as_float(v11 << 16), a0);
    a1 = fmaf(w11, __uint_as_float(v11 & 0xFFFF0000u), a1);
  }
  attn_out[(size_t)g * 16 + c] = (unsigned)f2bf(a0) | ((unsigned)f2bf(a1) << 16);
}

// ---------------- layer norm over 256: out = LN(x1 + x2) * gamma + beta
__global__ __launch_bounds__(64) void ln_kernel(const float* __restrict__ x1,
                                                const float* __restrict__ x2,
                                                const float* __restrict__ gamma,
                                                const float* __restrict__ beta,
                                                float* __restrict__ out) {
  const int row = blockIdx.x, lane = threadIdx.x;
  float4 a = ((const float4*)(x1 + (size_t)row * 256))[lane];
  float4 b = ((const float4*)(x2 + (size_t)row * 256))[lane];
  float v0 = a.x + b.x, v1 = a.y + b.y, v2 = a.z + b.z, v3 = a.w + b.w;
  float s1 = v0 + v1 + v2 + v3;
  float s2 = v0 * v0 + v1 * v1 + v2 * v2 + v3 * v3;
#pragma unroll
  for (int o = 1; o < 64; o <<= 1) { s1 += __shfl_xor(s1, o); s2 += __shfl_xor(s2, o); }
  const float mean = s1 * (1.f / 256.f);
  const float var = s2 * (1.f / 256.f) - mean * mean;
  const float rstd = rsqrtf(var + 1e-5f);
  float4 gm = ((const float4*)gamma)[lane];
  float4 bt = ((const float4*)beta)[lane];
  float4 o4;
  o4.x = (v0 - mean) * rstd * gm.x + bt.x;
  o4.y = (v1 - mean) * rstd * gm.y + bt.y;
  o4.z = (v2 - mean) * rstd * gm.z + bt.z;
  o4.w = (v3 - mean) * rstd * gm.w + bt.w;
  ((float4*)(out + (size_t)row * 256))[lane] = o4;
}

extern "C" void kernel_launch(void* const* d_in, const int* in_sizes, int n_in,
                              void* d_out, int out_size, void* d_ws, size_t ws_size,
                              hipStream_t stream) {
  (void)in_sizes; (void)n_in; (void)out_size; (void)ws_size;
  const float* cur_src = (const float*)d_in[0];
  const float* src_all = (const float*)d_in[1];
  const float* pos     = (const float*)d_in[2];
  const float* refp    = (const float*)d_in[3];
  const float* W_off   = (const float*)d_in[6];
  const float* b_off   = (const float*)d_in[7];
  const float* W_attn  = (const float*)d_in[8];
  const float* b_attn  = (const float*)d_in[9];
  const float* W_val   = (const float*)d_in[10];
  const float* b_val   = (const float*)d_in[11];
  const float* W_out   = (const float*)d_in[12];
  const float* b_out   = (const float*)d_in[13];
  const float* gamma1  = (const float*)d_in[14];
  const float* beta1   = (const float*)d_in[15];
  const float* W1      = (const float*)d_in[16];
  const float* b1      = (const float*)d_in[17];
  const float* W2      = (const float*)d_in[18];
  const float* b2      = (const float*)d_in[19];
  const float* gamma2  = (const float*)d_in[20];
  const float* beta2   = (const float*)d_in[21];
  float* out = (float*)d_out;

  // workspace layout (bytes); total 219,611,136 B (~209.4 MiB)
  char* ws = (char*)d_ws;
  unsigned short* value = (unsigned short*)(ws + 0);          // 67,108,864 B; reused as FFN hidden
  unsigned short* qbuf  = (unsigned short*)(ws + 67108864);   // 16,777,216 B
  float* offbuf         = (float*)(ws + 83886080);            // 33,554,432 B; reused as ffn_out
  float* attnl          = (float*)(ws + 117440512);           // 16,777,216 B
  unsigned short* attno = (unsigned short*)(ws + 134217728);  // 16,777,216 B
  float* src2           = (float*)(ws + 150994944);           // 33,554,432 B
  float* srcb           = (float*)(ws + 184549376);           // 33,554,432 B
  unsigned short* wt    = (unsigned short*)(ws + 218103808);  // bf16 weights
  unsigned short* wt_val  = wt;
  unsigned short* wt_off  = wt + 65536;
  unsigned short* wt_attn = wt + 131072;
  unsigned short* wt_out  = wt + 163840;
  unsigned short* wt_1    = wt + 229376;
  unsigned short* wt_2    = wt + 491520;

  // prep: weights -> bf16 NxK
  wtrans_kernel<<<256, 256, 0, stream>>>(W_val, wt_val, 256, 256);
  wtrans_kernel<<<256, 256, 0, stream>>>(W_off, wt_off, 256, 256);
  wtrans_kernel<<<128, 256, 0, stream>>>(W_attn, wt_attn, 256, 128);
  wtrans_kernel<<<256, 256, 0, stream>>>(W_out, wt_out, 256, 256);
  wtrans_kernel<<<1024, 256, 0, stream>>>(W1, wt_1, 256, 1024);
  wtrans_kernel<<<1024, 256, 0, stream>>>(W2, wt_2, 1024, 256);

  // q = cur_src + pos[:,3] (bf16)
  q_kernel<<<8192, 256, 0, stream>>>(cur_src, pos, qbuf);

  // value = (src_all + pos_flat) @ W_val + b_val  -> bf16
  gemm_kernel<0, 1, 0, 1><<<dim3(1024, 2), 256, 0, stream>>>(
      src_all, pos, wt_val, b_val, value, 131072, 256, 256);
  // off = q @ W_off + b_off  (f32)
  gemm_kernel<1, 0, 0, 0><<<dim3(256, 2), 256, 0, stream>>>(
      qbuf, nullptr, wt_off, b_off, offbuf, 32768, 256, 256);
  // attn logits = q @ W_attn + b_attn  (f32)
  gemm_kernel<1, 0, 0, 0><<<dim3(256, 1), 256, 0, stream>>>(
      qbuf, nullptr, wt_attn, b_attn, attnl, 32768, 128, 256);
  // deformable sampling -> attn_out bf16
  sample_kernel<<<16384, 256, 0, stream>>>(value, offbuf, attnl, refp,
                                           (unsigned int*)attno);
  // src2 = attn_out @ W_out + b_out (f32)
  gemm_kernel<1, 0, 0, 0><<<dim3(256, 2), 256, 0, stream>>>(
      attno, nullptr, wt_out, b_out, src2, 32768, 256, 256);
  // src = LN(cur_src + src2)
  ln_kernel<<<32768, 64, 0, stream>>>(cur_src, src2, gamma1, beta1, srcb);
  // h = relu(src @ W1 + b1) -> bf16 (reuses value buffer)
  gemm_kernel<0, 0, 1, 1><<<dim3(256, 8), 256, 0, stream>>>(
      srcb, nullptr, wt_1, b1, value, 32768, 1024, 256);
  // ffn_out = h @ W2 + b2 (f32, reuses offbuf)
  gemm_kernel<1, 0, 0, 0><<<dim3(256, 2), 256, 0, stream>>>(
      value, nullptr, wt_2, b2, offbuf, 32768, 256, 1024);
  // out = LN(src + ffn_out)
  ln_kernel<<<32768, 64, 0, stream>>>(srcb, offbuf, gamma2, beta2, out);
}

// Round 2
// 684.520 us; speedup vs baseline: 1.0171x; 1.0171x over previous
//
#include <hip/hip_runtime.h>

// Problem constants
#define LQN   16384     // queries per batch (128*128)
#define LINN  65536     // value length per batch (4 levels * 16384)

typedef __attribute__((ext_vector_type(8))) short bf16x8;
typedef __attribute__((ext_vector_type(4))) float f32x4;
typedef __attribute__((ext_vector_type(4))) unsigned short bf16x4;

__device__ __forceinline__ unsigned short f2bf(float f) {
  unsigned u = __float_as_uint(f);
  u += 0x7FFFu + ((u >> 16) & 1u);      // round-to-nearest-even
  return (unsigned short)(u >> 16);
}

// ---------------- fused weight transpose+convert for all 6 weights.
// wt layout (shorts): W_val[0,65536) W_off[65536,131072) W_attn[131072,163840)
// W_out[163840,229376) W1[229376,491520) W2[491520,753664). Total 753664.
__global__ __launch_bounds__(256) void wtrans6_kernel(
    const float* __restrict__ Wv, const float* __restrict__ Wo,
    const float* __restrict__ Wa, const float* __restrict__ Wu,
    const float* __restrict__ W1, const float* __restrict__ W2,
    unsigned short* __restrict__ wt) {
  int idx = blockIdx.x * 256 + threadIdx.x;     // grid = 2944 blocks exactly
  const float* W; int K, N, base;
  if (idx < 131072) {
    if (idx < 65536) { W = Wv; K = 256; N = 256; base = 0; }
    else             { W = Wo; K = 256; N = 256; base = 65536; }
  } else if (idx < 229376) {
    if (idx < 163840) { W = Wa; K = 256; N = 128; base = 131072; }
    else              { W = Wu; K = 256; N = 256; base = 163840; }
  } else if (idx < 491520) { W = W1; K = 256; N = 1024; base = 229376; }
  else                     { W = W2; K = 1024; N = 256; base = 491520; }
  int local = idx - base;
  int n = local / K, k = local - n * K;
  wt[idx] = f2bf(W[(size_t)k * N + n]);
}

// ---------------- q = cur_src + pos[:, 3]  (f32 -> bf16)
__global__ __launch_bounds__(256) void q_kernel(const float* __restrict__ cur,
                                                const float* __restrict__ pos,
                                                unsigned short* __restrict__ q) {
  size_t i = (size_t)blockIdx.x * 256 + threadIdx.x;  // float4 index, 2,097,152 total
  size_t row = i >> 6;                                // row in [0, 32768)
  int n = (int)(row >> 14), lq = (int)(row & 16383);
  float4 a = ((const float4*)cur)[i];
  float4 b = ((const float4*)pos)[(((size_t)n * 4 + 3) * LQN + lq) * 64 + (i & 63)];
  bf16x4 o;
  o.x = f2bf(a.x + b.x); o.y = f2bf(a.y + b.y);
  o.z = f2bf(a.z + b.z); o.w = f2bf(a.w + b.w);
  ((bf16x4*)q)[i] = o;
}

// ---------------- bf16 MFMA GEMM: C(MxN) = A(MxK) [+A2] @ B(KxN) + bias
// Bt is B pre-transposed to N x K bf16. 128x128 tile, BK=64, 4 waves (2x2 of 64x64).
// Staging is two-phase (all global loads -> regs, then convert -> LDS) for MLP.
template <int A_BF16, int HAS_A2, int DO_RELU, int OUT_BF16>
__global__ __launch_bounds__(256) void gemm_kernel(
    const void* __restrict__ Ap, const float* __restrict__ A2,
    const unsigned short* __restrict__ Bt, const float* __restrict__ bias,
    void* __restrict__ Cp, int M, int N, int K) {
  __shared__ unsigned short As[128][72];   // 64 + 8 pad (rows 144 B, 16B-aligned)
  __shared__ unsigned short Bs[128][72];
  const int tid = threadIdx.x;
  const int m0 = blockIdx.x * 128, n0 = blockIdx.y * 128;
  const int wave = tid >> 6, lane = tid & 63;
  const int wm = (wave >> 1) * 64, wn = (wave & 1) * 64;
  const int l15 = lane & 15, quad = lane >> 4;

  f32x4 acc[4][4];
#pragma unroll
  for (int i = 0; i < 4; i++)
#pragma unroll
    for (int j = 0; j < 4; j++)
#pragma unroll
      for (int r = 0; r < 4; r++) acc[i][j][r] = 0.f;

  for (int k0 = 0; k0 < K; k0 += 64) {
    if (A_BF16) {
      const unsigned short* A = (const unsigned short*)Ap;
      bf16x8 va[4], vb[4];
#pragma unroll
      for (int j = 0; j < 4; j++) {
        int c = tid + j * 256;                 // chunk of 8 bf16
        int row = c >> 3, ks = (c & 7) * 8;
        va[j] = *(const bf16x8*)(A + (size_t)(m0 + row) * K + k0 + ks);
      }
#pragma unroll
      for (int j = 0; j < 4; j++) {
        int c = tid + j * 256;
        int row = c >> 3, ks = (c & 7) * 8;
        vb[j] = *(const bf16x8*)(Bt + (size_t)(n0 + row) * K + k0 + ks);
      }
#pragma unroll
      for (int j = 0; j < 4; j++) {
        int c = tid + j * 256;
        int row = c >> 3, ks = (c & 7) * 8;
        *(bf16x8*)&As[row][ks] = va[j];
      }
#pragma unroll
      for (int j = 0; j < 4; j++) {
        int c = tid + j * 256;
        int row = c >> 3, ks = (c & 7) * 8;
        *(bf16x8*)&Bs[row][ks] = vb[j];
      }
    } else {
      const float* A = (const float*)Ap;
      float4 va[8], vw[8];
      bf16x8 vb[4];
#pragma unroll
      for (int j = 0; j < 8; j++) {
        int c = tid + j * 256;                 // chunk of 4 f32
        int row = c >> 4, ks = (c & 15) * 4;
        va[j] = *(const float4*)(A + (size_t)(m0 + row) * K + k0 + ks);
      }
      if (HAS_A2) {
#pragma unroll
        for (int j = 0; j < 8; j++) {
          int c = tid + j * 256;
          int row = c >> 4, ks = (c & 15) * 4;
          vw[j] = *(const float4*)(A2 + (size_t)(m0 + row) * K + k0 + ks);
        }
      }
#pragma unroll
      for (int j = 0; j < 4; j++) {
        int c = tid + j * 256;
        int row = c >> 3, ks = (c & 7) * 8;
        vb[j] = *(const bf16x8*)(Bt + (size_t)(n0 + row) * K + k0 + ks);
      }
#pragma unroll
      for (int j = 0; j < 8; j++) {
        int c = tid + j * 256;
        int row = c >> 4, ks = (c & 15) * 4;
        float4 v = va[j];
        if (HAS_A2) {
          v.x += vw[j].x; v.y += vw[j].y; v.z += vw[j].z; v.w += vw[j].w;
        }
        bf16x4 b;
        b.x = f2bf(v.x); b.y = f2bf(v.y); b.z = f2bf(v.z); b.w = f2bf(v.w);
        *(bf16x4*)&As[row][ks] = b;
      }
#pragma unroll
      for (int j = 0; j < 4; j++) {
        int c = tid + j * 256;
        int row = c >> 3, ks = (c & 7) * 8;
        *(bf16x8*)&Bs[row][ks] = vb[j];
      }
    }
    __syncthreads();
#pragma unroll
    for (int kk = 0; kk < 64; kk += 32) {
      bf16x8 af[4], bfr[4];
#pragma unroll
      for (int i = 0; i < 4; i++) af[i] = *(const bf16x8*)&As[wm + i * 16 + l15][kk + quad * 8];
#pragma unroll
      for (int j = 0; j < 4; j++) bfr[j] = *(const bf16x8*)&Bs[wn + j * 16 + l15][kk + quad * 8];
#pragma unroll
      for (int i = 0; i < 4; i++)
#pragma unroll
        for (int j = 0; j < 4; j++)
          acc[i][j] = __builtin_amdgcn_mfma_f32_16x16x32_bf16(af[i], bfr[j], acc[i][j], 0, 0, 0);
    }
    __syncthreads();
  }
  // ---- epilogue: bias (+relu), store
#pragma unroll
  for (int i = 0; i < 4; i++) {
#pragma unroll
    for (int j = 0; j < 4; j++) {
      const int col = n0 + wn + j * 16 + l15;
      const float bv = bias[col];
#pragma unroll
      for (int r = 0; r < 4; r++) {
        const int row = m0 + wm + i * 16 + quad * 4 + r;
        float v = acc[i][j][r] + bv;
        if (DO_RELU) v = fmaxf(v, 0.f);
        if (OUT_BF16)
          ((unsigned short*)Cp)[(size_t)row * N + col] = f2bf(v);
        else
          ((float*)Cp)[(size_t)row * N + col] = v;
      }
    }
  }
}

// ---------------- deformable sampling
// value: (2, LINN, 8, 32) bf16; offs: (2,LQ,8,4,4,2) f32; attnl: (2,LQ,128) f32;
// refp: (2,LQ,4,2) f32; out: (2,LQ,8,32) bf16 written as uint pairs.
// 16-lane subgroup per (n,lq,h); lane c handles channels 2c,2c+1.
__global__ __launch_bounds__(256) void sample_kernel(
    const unsigned short* __restrict__ value, const float* __restrict__ offs,
    const float* __restrict__ attnl, const float* __restrict__ refp,
    unsigned int* __restrict__ attn_out) {
  const int tid = threadIdx.x;
  const int sub = tid >> 4;
  const int c = tid & 15;
  const int g = blockIdx.x * 16 + sub;     // (n*LQ+lq)*8 + h, < 262144
  const int n = g >> 17;
  const int nl = g >> 3;                   // n*LQ + lq
  const int h = g & 7;

  // softmax over the 16 (level,point) logits (redundant per lane; broadcast loads)
  const float* lg = attnl + (size_t)nl * 128 + h * 16;
  float e[16];
  float mx = -1e30f;
#pragma unroll
  for (int i = 0; i < 16; i++) { e[i] = lg[i]; mx = fmaxf(mx, e[i]); }
  float s = 0.f;
#pragma unroll
  for (int i = 0; i < 16; i++) { e[i] = __expf(e[i] - mx); s += e[i]; }
  const float inv = 1.f / s;

  // this lane preps point pt = c (c in [0,16))
  const int pt = c;
  const int pl = pt >> 2;
  const float ox = offs[((size_t)g * 16 + pt) * 2 + 0];
  const float oy = offs[((size_t)g * 16 + pt) * 2 + 1];
  const float rx = refp[((size_t)nl * 4 + pl) * 2 + 0];
  const float ry = refp[((size_t)nl * 4 + pl) * 2 + 1];
  const float x = fmaf(rx, 128.f, ox - 0.5f);   // (ref + off/128)*128 - 0.5
  const float y = fmaf(ry, 128.f, oy - 0.5f);
  const float xf = floorf(x), yf = floorf(y);
  const float fx = x - xf, fy = y - yf;
  const int x0 = (int)xf, y0 = (int)yf;
  const float aw = e[pt] * inv;
  const int xc0 = min(max(x0, 0), 127), xc1 = min(max(x0 + 1, 0), 127);
  const int yc0 = min(max(y0, 0), 127), yc1 = min(max(y0 + 1, 0), 127);
  float wx0 = (x0 >= 0 && x0 <= 127) ? (1.f - fx) : 0.f;
  float wx1 = (x0 >= -1 && x0 <= 126) ? fx : 0.f;
  float wy0 = ((y0 >= 0 && y0 <= 127) ? (1.f - fy) : 0.f) * aw;
  float wy1 = ((y0 >= -1 && y0 <= 126) ? fy : 0.f) * aw;
  const int packed = xc0 | (xc1 << 7) | (yc0 << 14) | (yc1 << 21);

  // base pointer (uint = 2 channels); pixel stride = 256 bf16 = 128 uint
  const unsigned int* base0 =
      (const unsigned int*)value + (((size_t)n * LINN) * 8 + h) * 16 + c;

  float a0 = 0.f, a1 = 0.f;
#pragma unroll
  for (int p = 0; p < 16; p++) {
    const int pk = __shfl(packed, p, 16);
    const float w_x0 = __shfl(wx0, p, 16);
    const float w_x1 = __shfl(wx1, p, 16);
    const float w_y0 = __shfl(wy0, p, 16);
    const float w_y1 = __shfl(wy1, p, 16);
    const unsigned int* bl = base0 + (size_t)(p >> 2) * (LQN * 128);
    const int X0 = pk & 127, X1 = (pk >> 7) & 127;
    const int Y0 = (pk >> 14) & 127, Y1 = (pk >> 21) & 127;
    const unsigned v00 = bl[(Y0 * 128 + X0) * 128];
    const unsigned v01 = bl[(Y0 * 128 + X1) * 128];
    const unsigned v10 = bl[(Y1 * 128 + X0) * 128];
    const unsigned v11 = bl[(Y1 * 128 + X1) * 128];
    const float w00 = w_x0 * w_y0, w01 = w_x1 * w_y0;
    const float w10 = w_x0 * w_y1, w11 = w_x1 * w_y1;
    a0 = fmaf(w00, __uint_as_float(v00 << 16), a0);
    a1 = fmaf(w00, __uint_as_float(v00 & 0xFFFF0000u), a1);
    a0 = fmaf(w01, __uint_as_float(v01 << 16), a0);
    a1 = fmaf(w01, __uint_as_float(v01 & 0xFFFF0000u), a1);
    a0 = fmaf(w10, __uint_as_float(v10 << 16), a0);
    a1 = fmaf(w10, __uint_as_float(v10 & 0xFFFF0000u), a1);
    a0 = fmaf(w11, __uint_as_float(v11 << 16), a0);
    a1 = fmaf(w11, __uint_as_float(v11 & 0xFFFF0000u), a1);
  }
  attn_out[(size_t)g * 16 + c] = (unsigned)f2bf(a0) | ((unsigned)f2bf(a1) << 16);
}

// ---------------- layer norm over 256: out = LN(x1 + x2) * gamma + beta
// 256 threads = 4 waves, one row per wave. Optionally also emits bf16 copy.
template <int EMIT_BF16>
__global__ __launch_bounds__(256) void ln_kernel(const float* __restrict__ x1,
                                                 const float* __restrict__ x2,
                                                 const float* __restrict__ gamma,
                                                 const float* __restrict__ beta,
                                                 float* __restrict__ out,
                                                 unsigned short* __restrict__ outb) {
  const int row = blockIdx.x * 4 + (threadIdx.x >> 6);
  const int lane = threadIdx.x & 63;
  float4 a = ((const float4*)(x1 + (size_t)row * 256))[lane];
  float4 b = ((const float4*)(x2 + (size_t)row * 256))[lane];
  float v0 = a.x + b.x, v1 = a.y + b.y, v2 = a.z + b.z, v3 = a.w + b.w;
  float s1 = v0 + v1 + v2 + v3;
  float s2 = v0 * v0 + v1 * v1 + v2 * v2 + v3 * v3;
#pragma unroll
  for (int o = 1; o < 64; o <<= 1) { s1 += __shfl_xor(s1, o); s2 += __shfl_xor(s2, o); }
  const float mean = s1 * (1.f / 256.f);
  const float var = s2 * (1.f / 256.f) - mean * mean;
  const float rstd = rsqrtf(var + 1e-5f);
  float4 gm = ((const float4*)gamma)[lane];
  float4 bt = ((const float4*)beta)[lane];
  float4 o4;
  o4.x = (v0 - mean) * rstd * gm.x + bt.x;
  o4.y = (v1 - mean) * rstd * gm.y + bt.y;
  o4.z = (v2 - mean) * rstd * gm.z + bt.z;
  o4.w = (v3 - mean) * rstd * gm.w + bt.w;
  ((float4*)(out + (size_t)row * 256))[lane] = o4;
  if (EMIT_BF16) {
    bf16x4 ob;
    ob.x = f2bf(o4.x); ob.y = f2bf(o4.y); ob.z = f2bf(o4.z); ob.w = f2bf(o4.w);
    ((bf16x4*)(outb + (size_t)row * 256))[lane] = ob;
  }
}

extern "C" void kernel_launch(void* const* d_in, const int* in_sizes, int n_in,
                              void* d_out, int out_size, void* d_ws, size_t ws_size,
                              hipStream_t stream) {
  (void)in_sizes; (void)n_in; (void)out_size; (void)ws_size;
  const float* cur_src = (const float*)d_in[0];
  const float* src_all = (const float*)d_in[1];
  const float* pos     = (const float*)d_in[2];
  const float* refp    = (const float*)d_in[3];
  const float* W_off   = (const float*)d_in[6];
  const float* b_off   = (const float*)d_in[7];
  const float* W_attn  = (const float*)d_in[8];
  const float* b_attn  = (const float*)d_in[9];
  const float* W_val   = (const float*)d_in[10];
  const float* b_val   = (const float*)d_in[11];
  const float* W_out   = (const float*)d_in[12];
  const float* b_out   = (const float*)d_in[13];
  const float* gamma1  = (const float*)d_in[14];
  const float* beta1   = (const float*)d_in[15];
  const float* W1      = (const float*)d_in[16];
  const float* b1      = (const float*)d_in[17];
  const float* W2      = (const float*)d_in[18];
  const float* b2      = (const float*)d_in[19];
  const float* gamma2  = (const float*)d_in[20];
  const float* beta2   = (const float*)d_in[21];
  float* out = (float*)d_out;

  // workspace layout (bytes); total ~209.4 MiB (same as round 1)
  char* ws = (char*)d_ws;
  unsigned short* value = (unsigned short*)(ws + 0);          // 67,108,864 B; reused as FFN hidden
  unsigned short* qbuf  = (unsigned short*)(ws + 67108864);   // 16,777,216 B
  float* offbuf         = (float*)(ws + 83886080);            // 33,554,432 B; reused as ffn_out
  float* attnl          = (float*)(ws + 117440512);           // 16,777,216 B; reused as srcb_bf16
  unsigned short* attno = (unsigned short*)(ws + 134217728);  // 16,777,216 B
  float* src2           = (float*)(ws + 150994944);           // 33,554,432 B
  float* srcb           = (float*)(ws + 184549376);           // 33,554,432 B
  unsigned short* wt    = (unsigned short*)(ws + 218103808);  // bf16 weights (1.5 MB)
  unsigned short* wt_val  = wt;
  unsigned short* wt_off  = wt + 65536;
  unsigned short* wt_attn = wt + 131072;
  unsigned short* wt_out  = wt + 163840;
  unsigned short* wt_1    = wt + 229376;
  unsigned short* wt_2    = wt + 491520;
  unsigned short* srcb_bf = (unsigned short*)attnl;           // attnl dead after sample

  // prep: all weights -> bf16 NxK in one launch
  wtrans6_kernel<<<2944, 256, 0, stream>>>(W_val, W_off, W_attn, W_out, W1, W2, wt);

  // q = cur_src + pos[:,3] (bf16)
  q_kernel<<<8192, 256, 0, stream>>>(cur_src, pos, qbuf);

  // value = (src_all + pos_flat) @ W_val + b_val  -> bf16
  gemm_kernel<0, 1, 0, 1><<<dim3(1024, 2), 256, 0, stream>>>(
      src_all, pos, wt_val, b_val, value, 131072, 256, 256);
  // off = q @ W_off + b_off  (f32)
  gemm_kernel<1, 0, 0, 0><<<dim3(256, 2), 256, 0, stream>>>(
      qbuf, nullptr, wt_off, b_off, offbuf, 32768, 256, 256);
  // attn logits = q @ W_attn + b_attn  (f32)
  gemm_kernel<1, 0, 0, 0><<<dim3(256, 1), 256, 0, stream>>>(
      qbuf, nullptr, wt_attn, b_attn, attnl, 32768, 128, 256);
  // deformable sampling -> attn_out bf16
  sample_kernel<<<16384, 256, 0, stream>>>(value, offbuf, attnl, refp,
                                           (unsigned int*)attno);
  // src2 = attn_out @ W_out + b_out (f32)
  gemm_kernel<1, 0, 0, 0><<<dim3(256, 2), 256, 0, stream>>>(
      attno, nullptr, wt_out, b_out, src2, 32768, 256, 256);
  // src = LN(cur_src + src2) -> f32 srcb + bf16 srcb_bf
  ln_kernel<1><<<8192, 256, 0, stream>>>(cur_src, src2, gamma1, beta1, srcb, srcb_bf);
  // h = relu(src @ W1 + b1) -> bf16 (reuses value buffer)
  gemm_kernel<1, 0, 1, 1><<<dim3(256, 8), 256, 0, stream>>>(
      srcb_bf, nullptr, wt_1, b1, value, 32768, 1024, 256);
  // ffn_out = h @ W2 + b2 (f32, reuses offbuf)
  gemm_kernel<1, 0, 0, 0><<<dim3(256, 2), 256, 0, stream>>>(
      value, nullptr, wt_2, b2, offbuf, 32768, 256, 1024);
  // out = LN(src + ffn_out)
  ln_kernel<0><<<8192, 256, 0, stream>>>(srcb, offbuf, gamma2, beta2, out, nullptr);
}

// Round 3
// 646.589 us; speedup vs baseline: 1.0768x; 1.0587x over previous
//
#include <hip/hip_runtime.h>

// Problem constants
#define LQN   16384     // queries per batch (128*128)
#define LINN  65536     // value length per batch (4 levels * 16384)

typedef __attribute__((ext_vector_type(8))) short bf16x8;
typedef __attribute__((ext_vector_type(4))) float f32x4;
typedef __attribute__((ext_vector_type(4))) unsigned short bf16x4;

__device__ __forceinline__ unsigned short f2bf(float f) {
  unsigned u = __float_as_uint(f);
  u += 0x7FFFu + ((u >> 16) & 1u);      // round-to-nearest-even
  return (unsigned short)(u >> 16);
}

// ---------------- fused weight transpose+convert for all 6 weights.
// wt layout (shorts): W_val[0,65536) W_off[65536,131072) W_attn[131072,163840)
// W_out[163840,229376) W1[229376,491520) W2[491520,753664). Total 753664.
// NOTE: W_off then W_attn contiguous => combined 384xK matrix for the merged GEMM.
__global__ __launch_bounds__(256) void wtrans6_kernel(
    const float* __restrict__ Wv, const float* __restrict__ Wo,
    const float* __restrict__ Wa, const float* __restrict__ Wu,
    const float* __restrict__ W1, const float* __restrict__ W2,
    unsigned short* __restrict__ wt) {
  int idx = blockIdx.x * 256 + threadIdx.x;     // grid = 2944 blocks exactly
  const float* W; int K, N, base;
  if (idx < 131072) {
    if (idx < 65536) { W = Wv; K = 256; N = 256; base = 0; }
    else             { W = Wo; K = 256; N = 256; base = 65536; }
  } else if (idx < 229376) {
    if (idx < 163840) { W = Wa; K = 256; N = 128; base = 131072; }
    else              { W = Wu; K = 256; N = 256; base = 163840; }
  } else if (idx < 491520) { W = W1; K = 256; N = 1024; base = 229376; }
  else                     { W = W2; K = 1024; N = 256; base = 491520; }
  int local = idx - base;
  int n = local / K, k = local - n * K;
  wt[idx] = f2bf(W[(size_t)k * N + n]);
}

// ---------------- streaming add+convert: inp_bf = bf16(src_all + pos_flat)
// and qbuf = bf16(cur_src + pos[:,3]). One float4 per thread.
__global__ __launch_bounds__(256) void addcvt_kernel(
    const float* __restrict__ src_all, const float* __restrict__ pos,
    const float* __restrict__ cur, unsigned short* __restrict__ inp_bf,
    unsigned short* __restrict__ qb) {
  size_t i = (size_t)blockIdx.x * 256 + threadIdx.x;  // < 10,485,760
  if (i < 8388608) {
    float4 a = ((const float4*)src_all)[i];
    float4 b = ((const float4*)pos)[i];     // pos flat matches src_all row order
    bf16x4 o;
    o.x = f2bf(a.x + b.x); o.y = f2bf(a.y + b.y);
    o.z = f2bf(a.z + b.z); o.w = f2bf(a.w + b.w);
    ((bf16x4*)inp_bf)[i] = o;
  } else {
    size_t j = i - 8388608;
    size_t row = j >> 6;                    // [0, 32768)
    int n = (int)(row >> 14), lq = (int)(row & 16383);
    float4 a = ((const float4*)cur)[j];
    float4 b = ((const float4*)pos)[(((size_t)n * 4 + 3) * LQN + lq) * 64 + (j & 63)];
    bf16x4 o;
    o.x = f2bf(a.x + b.x); o.y = f2bf(a.y + b.y);
    o.z = f2bf(a.z + b.z); o.w = f2bf(a.w + b.w);
    ((bf16x4*)qb)[j] = o;
  }
}

// ---------------- bf16 MFMA GEMM, m97-style global_load_lds staging.
// A: M x K bf16 row-major. Bt: N x K bf16 (pre-transposed). 128x128 tile,
// BK=64, 4 waves (2x2 of 64x64). LDS unpadded, XOR source-swizzle: physical
// 16B chunk p of row r holds logical chunk p^(r&7); reads become 2-way (free).
// 1D grid, y-fast: by = bid % ny (N tile), bx = bid / ny (M tile).
// SPLIT=1: cols [0,256) -> Cp (stride 256) + bias, cols [256,384) -> Cp2
// (stride 128) + bias2 (block-uniform branch; tiles are pure).
template <int DO_RELU, int OUT_BF16, int SPLIT>
__global__ __launch_bounds__(256) void gemm_lds_kernel(
    const unsigned short* __restrict__ A, const unsigned short* __restrict__ Bt,
    const float* __restrict__ bias, const float* __restrict__ bias2,
    void* __restrict__ Cp, float* __restrict__ Cp2,
    int M, int N, int K, int ny) {
  __shared__ unsigned short As[128 * 64];
  __shared__ unsigned short Bs[128 * 64];
  const int bid = blockIdx.x;
  const int by = bid % ny, bx = bid / ny;
  const int m0 = bx * 128, n0 = by * 128;
  const int tid = threadIdx.x;
  const int wave = tid >> 6, lane = tid & 63;
  const int wm = (wave >> 1) * 64, wn = (wave & 1) * 64;
  const int l15 = lane & 15, quad = lane >> 4;
  const int rl = lane >> 3;                 // row within 8-row slab
  const int cl = (lane & 7) ^ rl;           // swizzled source chunk (16B units)

  f32x4 acc[4][4];
#pragma unroll
  for (int i = 0; i < 4; i++)
#pragma unroll
    for (int j = 0; j < 4; j++)
#pragma unroll
      for (int r = 0; r < 4; r++) acc[i][j][r] = 0.f;

  const unsigned short* Abase = A + (size_t)m0 * K + cl * 8;
  const unsigned short* Bbase = Bt + (size_t)n0 * K + cl * 8;

  for (int k0 = 0; k0 < K; k0 += 64) {
    // ---- async stage: each wave covers 32 rows of As and Bs (4 issues each)
#pragma unroll
    for (int t = 0; t < 4; t++) {
      const int row = wave * 32 + t * 8 + rl;
      __builtin_amdgcn_global_load_lds(
          (const __attribute__((address_space(1))) void*)(Abase + (size_t)row * K + k0),
          (__attribute__((address_space(3))) void*)(As + (wave * 32 + t * 8) * 64),
          16, 0, 0);
      __builtin_amdgcn_global_load_lds(
          (const __attribute__((address_space(1))) void*)(Bbase + (size_t)row * K + k0),
          (__attribute__((address_space(3))) void*)(Bs + (wave * 32 + t * 8) * 64),
          16, 0, 0);
    }
    __syncthreads();   // drains vmcnt(0) then barrier: LDS tiles ready
#pragma unroll
    for (int kk = 0; kk < 2; kk++) {
      bf16x8 af[4], bfr[4];
#pragma unroll
      for (int i = 0; i < 4; i++) {
        const int row = wm + i * 16 + l15;
        af[i] = *(const bf16x8*)&As[row * 64 + (((quad + 4 * kk) ^ (row & 7)) * 8)];
      }
#pragma unroll
      for (int j = 0; j < 4; j++) {
        const int row = wn + j * 16 + l15;
        bfr[j] = *(const bf16x8*)&Bs[row * 64 + (((quad + 4 * kk) ^ (row & 7)) * 8)];
      }
#pragma unroll
      for (int i = 0; i < 4; i++)
#pragma unroll
        for (int j = 0; j < 4; j++)
          acc[i][j] = __builtin_amdgcn_mfma_f32_16x16x32_bf16(af[i], bfr[j], acc[i][j], 0, 0, 0);
    }
    __syncthreads();   // protect LDS before next-iter overwrite
  }
  // ---- epilogue: bias (+relu), store
#pragma unroll
  for (int i = 0; i < 4; i++) {
#pragma unroll
    for (int j = 0; j < 4; j++) {
      const int col = n0 + wn + j * 16 + l15;
      float bv;
      if (SPLIT) bv = (col < 256) ? bias[col] : bias2[col - 256];
      else       bv = bias[col];
#pragma unroll
      for (int r = 0; r < 4; r++) {
        const int row = m0 + wm + i * 16 + quad * 4 + r;
        float v = acc[i][j][r] + bv;
        if (DO_RELU) v = fmaxf(v, 0.f);
        if (SPLIT) {
          if (col < 256) ((float*)Cp)[(size_t)row * 256 + col] = v;
          else           Cp2[(size_t)row * 128 + (col - 256)] = v;
        } else if (OUT_BF16) {
          ((unsigned short*)Cp)[(size_t)row * N + col] = f2bf(v);
        } else {
          ((float*)Cp)[(size_t)row * N + col] = v;
        }
      }
    }
  }
}

// ---------------- deformable sampling
// value: (2, LINN, 8, 32) bf16; offs: (2,LQ,8,4,4,2) f32; attnl: (2,LQ,128) f32;
// refp: (2,LQ,4,2) f32; out: (2,LQ,8,32) bf16 written as uint pairs.
// 16-lane subgroup per (n,lq,h); lane c handles channels 2c,2c+1.
__global__ __launch_bounds__(256) void sample_kernel(
    const unsigned short* __restrict__ value, const float* __restrict__ offs,
    const float* __restrict__ attnl, const float* __restrict__ refp,
    unsigned int* __restrict__ attn_out) {
  const int tid = threadIdx.x;
  const int sub = tid >> 4;
  const int c = tid & 15;
  const int g = blockIdx.x * 16 + sub;     // (n*LQ+lq)*8 + h, < 262144
  const int n = g >> 17;
  const int nl = g >> 3;                   // n*LQ + lq
  const int h = g & 7;

  // softmax over the 16 (level,point) logits (redundant per lane; broadcast loads)
  const float* lg = attnl + (size_t)nl * 128 + h * 16;
  float e[16];
  float mx = -1e30f;
#pragma unroll
  for (int i = 0; i < 16; i++) { e[i] = lg[i]; mx = fmaxf(mx, e[i]); }
  float s = 0.f;
#pragma unroll
  for (int i = 0; i < 16; i++) { e[i] = __expf(e[i] - mx); s += e[i]; }
  const float inv = 1.f / s;

  // this lane preps point pt = c (c in [0,16))
  const int pt = c;
  const int pl = pt >> 2;
  const float ox = offs[((size_t)g * 16 + pt) * 2 + 0];
  const float oy = offs[((size_t)g * 16 + pt) * 2 + 1];
  const float rx = refp[((size_t)nl * 4 + pl) * 2 + 0];
  const float ry = refp[((size_t)nl * 4 + pl) * 2 + 1];
  const float x = fmaf(rx, 128.f, ox - 0.5f);   // (ref + off/128)*128 - 0.5
  const float y = fmaf(ry, 128.f, oy - 0.5f);
  const float xf = floorf(x), yf = floorf(y);
  const float fx = x - xf, fy = y - yf;
  const int x0 = (int)xf, y0 = (int)yf;
  const float aw = e[pt] * inv;
  const int xc0 = min(max(x0, 0), 127), xc1 = min(max(x0 + 1, 0), 127);
  const int yc0 = min(max(y0, 0), 127), yc1 = min(max(y0 + 1, 0), 127);
  float wx0 = (x0 >= 0 && x0 <= 127) ? (1.f - fx) : 0.f;
  float wx1 = (x0 >= -1 && x0 <= 126) ? fx : 0.f;
  float wy0 = ((y0 >= 0 && y0 <= 127) ? (1.f - fy) : 0.f) * aw;
  float wy1 = ((y0 >= -1 && y0 <= 126) ? fy : 0.f) * aw;
  const int packed = xc0 | (xc1 << 7) | (yc0 << 14) | (yc1 << 21);

  // base pointer (uint = 2 channels); pixel stride = 256 bf16 = 128 uint
  const unsigned int* base0 =
      (const unsigned int*)value + (((size_t)n * LINN) * 8 + h) * 16 + c;

  float a0 = 0.f, a1 = 0.f;
#pragma unroll
  for (int p = 0; p < 16; p++) {
    const int pk = __shfl(packed, p, 16);
    const float w_x0 = __shfl(wx0, p, 16);
    const float w_x1 = __shfl(wx1, p, 16);
    const float w_y0 = __shfl(wy0, p, 16);
    const float w_y1 = __shfl(wy1, p, 16);
    const unsigned int* bl = base0 + (size_t)(p >> 2) * (LQN * 128);
    const int X0 = pk & 127, X1 = (pk >> 7) & 127;
    const int Y0 = (pk >> 14) & 127, Y1 = (pk >> 21) & 127;
    const unsigned v00 = bl[(Y0 * 128 + X0) * 128];
    const unsigned v01 = bl[(Y0 * 128 + X1) * 128];
    const unsigned v10 = bl[(Y1 * 128 + X0) * 128];
    const unsigned v11 = bl[(Y1 * 128 + X1) * 128];
    const float w00 = w_x0 * w_y0, w01 = w_x1 * w_y0;
    const float w10 = w_x0 * w_y1, w11 = w_x1 * w_y1;
    a0 = fmaf(w00, __uint_as_float(v00 << 16), a0);
    a1 = fmaf(w00, __uint_as_float(v00 & 0xFFFF0000u), a1);
    a0 = fmaf(w01, __uint_as_float(v01 << 16), a0);
    a1 = fmaf(w01, __uint_as_float(v01 & 0xFFFF0000u), a1);
    a0 = fmaf(w10, __uint_as_float(v10 << 16), a0);
    a1 = fmaf(w10, __uint_as_float(v10 & 0xFFFF0000u), a1);
    a0 = fmaf(w11, __uint_as_float(v11 << 16), a0);
    a1 = fmaf(w11, __uint_as_float(v11 & 0xFFFF0000u), a1);
  }
  attn_out[(size_t)g * 16 + c] = (unsigned)f2bf(a0) | ((unsigned)f2bf(a1) << 16);
}

// ---------------- layer norm over 256: out = LN(x1 + x2) * gamma + beta
// 256 threads = 4 waves, one row per wave. Optionally also emits bf16 copy.
template <int EMIT_BF16>
__global__ __launch_bounds__(256) void ln_kernel(const float* __restrict__ x1,
                                                 const float* __restrict__ x2,
                                                 const float* __restrict__ gamma,
                                                 const float* __restrict__ beta,
                                                 float* __restrict__ out,
                                                 unsigned short* __restrict__ outb) {
  const int row = blockIdx.x * 4 + (threadIdx.x >> 6);
  const int lane = threadIdx.x & 63;
  float4 a = ((const float4*)(x1 + (size_t)row * 256))[lane];
  float4 b = ((const float4*)(x2 + (size_t)row * 256))[lane];
  float v0 = a.x + b.x, v1 = a.y + b.y, v2 = a.z + b.z, v3 = a.w + b.w;
  float s1 = v0 + v1 + v2 + v3;
  float s2 = v0 * v0 + v1 * v1 + v2 * v2 + v3 * v3;
#pragma unroll
  for (int o = 1; o < 64; o <<= 1) { s1 += __shfl_xor(s1, o); s2 += __shfl_xor(s2, o); }
  const float mean = s1 * (1.f / 256.f);
  const float var = s2 * (1.f / 256.f) - mean * mean;
  const float rstd = rsqrtf(var + 1e-5f);
  float4 gm = ((const float4*)gamma)[lane];
  float4 bt = ((const float4*)beta)[lane];
  float4 o4;
  o4.x = (v0 - mean) * rstd * gm.x + bt.x;
  o4.y = (v1 - mean) * rstd * gm.y + bt.y;
  o4.z = (v2 - mean) * rstd * gm.z + bt.z;
  o4.w = (v3 - mean) * rstd * gm.w + bt.w;
  ((float4*)(out + (size_t)row * 256))[lane] = o4;
  if (EMIT_BF16) {
    bf16x4 ob;
    ob.x = f2bf(o4.x); ob.y = f2bf(o4.y); ob.z = f2bf(o4.z); ob.w = f2bf(o4.w);
    ((bf16x4*)(outb + (size_t)row * 256))[lane] = ob;
  }
}

extern "C" void kernel_launch(void* const* d_in, const int* in_sizes, int n_in,
                              void* d_out, int out_size, void* d_ws, size_t ws_size,
                              hipStream_t stream) {
  (void)in_sizes; (void)n_in; (void)out_size; (void)ws_size;
  const float* cur_src = (const float*)d_in[0];
  const float* src_all = (const float*)d_in[1];
  const float* pos     = (const float*)d_in[2];
  const float* refp    = (const float*)d_in[3];
  const float* W_off   = (const float*)d_in[6];
  const float* b_off   = (const float*)d_in[7];
  const float* W_attn  = (const float*)d_in[8];
  const float* b_attn  = (const float*)d_in[9];
  const float* W_val   = (const float*)d_in[10];
  const float* b_val   = (const float*)d_in[11];
  const float* W_out   = (const float*)d_in[12];
  const float* b_out   = (const float*)d_in[13];
  const float* gamma1  = (const float*)d_in[14];
  const float* beta1   = (const float*)d_in[15];
  const float* W1      = (const float*)d_in[16];
  const float* b1      = (const float*)d_in[17];
  const float* W2      = (const float*)d_in[18];
  const float* b2      = (const float*)d_in[19];
  const float* gamma2  = (const float*)d_in[20];
  const float* beta2   = (const float*)d_in[21];
  float* out = (float*)d_out;

  // workspace layout (bytes); total ~209.4 MiB (unchanged from round 1/2)
  char* ws = (char*)d_ws;
  unsigned short* value = (unsigned short*)(ws + 0);          // 67,108,864 B; reused as FFN hidden
  unsigned short* qbuf  = (unsigned short*)(ws + 67108864);   // 16,777,216 B
  float* offbuf         = (float*)(ws + 83886080);            // 33,554,432 B; reused as ffn_out
  float* attnl          = (float*)(ws + 117440512);           // 16,777,216 B; reused as srcb_bf16
  unsigned short* attno = (unsigned short*)(ws + 134217728);  // 16,777,216 B
  float* src2           = (float*)(ws + 150994944);           // 33,554,432 B
  float* srcb           = (float*)(ws + 184549376);           // 33,554,432 B
  unsigned short* wt    = (unsigned short*)(ws + 218103808);  // bf16 weights (1.5 MB)
  unsigned short* wt_val  = wt;
  unsigned short* wt_qa   = wt + 65536;   // W_off(256xK) ++ W_attn(128xK) contiguous
  unsigned short* wt_out  = wt + 163840;
  unsigned short* wt_1    = wt + 229376;
  unsigned short* wt_2    = wt + 491520;
  unsigned short* srcb_bf = (unsigned short*)attnl;           // attnl dead after sample
  // inp_bf (131072x256 bf16 = 64 MiB) overlays src2+srcb (dead until out-proj)
  unsigned short* inp_bf  = (unsigned short*)src2;

  // prep: all weights -> bf16 NxK in one launch
  wtrans6_kernel<<<2944, 256, 0, stream>>>(W_val, W_off, W_attn, W_out, W1, W2, wt);

  // inp_bf = bf16(src_all + pos_flat); qbuf = bf16(cur_src + pos[:,3])
  addcvt_kernel<<<40960, 256, 0, stream>>>(src_all, pos, cur_src, inp_bf, qbuf);

  // value = inp_bf @ W_val + b_val  -> bf16
  gemm_lds_kernel<0, 1, 0><<<2048, 256, 0, stream>>>(
      inp_bf, wt_val, b_val, nullptr, value, nullptr, 131072, 256, 256, 2);
  // [off | attn logits] = qbuf @ [W_off | W_attn] (merged N=384, split epilogue)
  gemm_lds_kernel<0, 0, 1><<<768, 256, 0, stream>>>(
      qbuf, wt_qa, b_off, b_attn, offbuf, attnl, 32768, 384, 256, 3);
  // deformable sampling -> attn_out bf16
  sample_kernel<<<16384, 256, 0, stream>>>(value, offbuf, attnl, refp,
                                           (unsigned int*)attno);
  // src2 = attn_out @ W_out + b_out (f32)  [overwrites inp_bf region: dead]
  gemm_lds_kernel<0, 0, 0><<<512, 256, 0, stream>>>(
      attno, wt_out, b_out, nullptr, src2, nullptr, 32768, 256, 256, 2);
  // src = LN(cur_src + src2) -> f32 srcb + bf16 srcb_bf
  ln_kernel<1><<<8192, 256, 0, stream>>>(cur_src, src2, gamma1, beta1, srcb, srcb_bf);
  // h = relu(src @ W1 + b1) -> bf16 (reuses value buffer; sample already done)
  gemm_lds_kernel<1, 1, 0><<<2048, 256, 0, stream>>>(
      srcb_bf, wt_1, b1, nullptr, value, nullptr, 32768, 1024, 256, 8);
  // ffn_out = h @ W2 + b2 (f32, reuses offbuf)
  gemm_lds_kernel<0, 0, 0><<<512, 256, 0, stream>>>(
      value, wt_2, b2, nullptr, offbuf, nullptr, 32768, 256, 1024, 2);
  // out = LN(src + ffn_out)
  ln_kernel<0><<<8192, 256, 0, stream>>>(srcb, offbuf, gamma2, beta2, out, nullptr);
}